// Round 11
// baseline (832.452 us; speedup 1.0000x reference)
//
#include <hip/hip_runtime.h>

typedef unsigned int UI;
typedef unsigned long long ULL;
typedef _Float16 f16;
typedef _Float16 h8 __attribute__((ext_vector_type(8)));
typedef float f32x4 __attribute__((ext_vector_type(4)));
typedef float fl2 __attribute__((ext_vector_type(2)));

#define NB_PTS 4096
#define MB_SEL 1024
#define KNBR   64
#define NCLOUD 4
#define NCENT  (NCLOUD * MB_SEL)

// ws layout (f16): Wt1[128][96] @0 ; Wt2[128][128] @12288 ; Wt3[256][128] @28672
#define WT2_OFF 12288
#define WT3_OFF 28672
#define WS_ELEMS 61440
#define PREP_BLOCKS 120   // 61440 / 512

// exact np-order squared distance, f64 (radius predicate — proven)
__device__ __forceinline__ double d2_np64(double dx, double dy, double dz) {
  return __dadd_rn(__dadd_rn(__dmul_rn(dx, dx), __dmul_rn(dy, dy)),
                   __dmul_rn(dz, dz));
}

// DPP reduce steps: idempotent ops, old=self (disabled lanes keep own value)
template <int CTRL>
__device__ __forceinline__ float dpp_maxf(float v) {
  int o = __builtin_amdgcn_update_dpp(__float_as_int(v), __float_as_int(v),
                                      CTRL, 0xf, 0xf, false);
  return fmaxf(v, __int_as_float(o));
}
template <int CTRL>
__device__ __forceinline__ UI dpp_minu(UI v) {
  UI o = (UI)__builtin_amdgcn_update_dpp((int)v, (int)v, CTRL, 0xf, 0xf, false);
  return v < o ? v : o;
}

// ---------------------------------------------------------------------------
// Kernel 1: blocks 0..3 = FPS (exact np-f32); blocks 4..123 = weight prep.
// FPS: 512 thr x 8 pts. Wave reduce: f32-max DPP chain + readlane, then u32
// idx-min DPP chain (tie-break). One u64 key per wave -> LDS, ONE barrier.
// ---------------------------------------------------------------------------
__global__ __launch_bounds__(512) void fps_prep_kernel(
    const float* __restrict__ pos, float* __restrict__ selstash,
    const float* __restrict__ W1, const float* __restrict__ W2,
    const float* __restrict__ W3, f16* __restrict__ ws) {
#pragma clang fp contract(off)
  __shared__ float4 pp[NB_PTS];     // 64 KB: (x,y,z,pad)
  __shared__ ULL slots[2][8];

  if (blockIdx.x >= NCLOUD) {       // ---- prep path ----
    int t = (int)(blockIdx.x - NCLOUD) * 512 + threadIdx.x;
    if (t < WT2_OFF) {                       // Wt1[n][k] : 128 x 96
      int n = t / 96, k = t - n * 96;
      ws[t] = (k < 67) ? (f16)W1[k * 128 + n] : (f16)0.f;
    } else if (t < WT3_OFF) {                // Wt2[n][k] : 128 x 128
      int u = t - WT2_OFF;
      int n = u >> 7, k = u & 127;
      ws[t] = (f16)W2[k * 128 + n];
    } else if (t < WS_ELEMS) {               // Wt3[n][k] : 256 x 128
      int u = t - WT3_OFF;
      int n = u >> 7, k = u & 127;
      ws[t] = (f16)W3[k * 256 + n];
    }
    return;
  }

  const int b    = blockIdx.x;
  const int tid  = threadIdx.x;
  const int lane = tid & 63;
  const int wv   = tid >> 6;

  fl2 mx[4], my[4], mz[4], dist[4];
#pragma unroll
  for (int t = 0; t < 4; ++t) {
    int j0 = tid + (2 * t) * 512;
    int j1 = tid + (2 * t + 1) * 512;
    size_t a0 = ((size_t)b * NB_PTS + j0) * 3;
    size_t a1 = ((size_t)b * NB_PTS + j1) * 3;
    float X0 = pos[a0], Y0 = pos[a0 + 1], Z0 = pos[a0 + 2];
    float X1 = pos[a1], Y1 = pos[a1 + 1], Z1 = pos[a1 + 2];
    pp[j0] = make_float4(X0, Y0, Z0, 0.f);
    pp[j1] = make_float4(X1, Y1, Z1, 0.f);
    mx[t] = fl2{X0, X1}; my[t] = fl2{Y0, Y1}; mz[t] = fl2{Z0, Z1};
    dist[t] = fl2{__builtin_inff(), __builtin_inff()};
  }
  if (tid == 0) selstash[b * MB_SEL] = 0.0f;
  __syncthreads();

  int cur = 0;
  for (int k = 1; k < MB_SEL; ++k) {
    float4 w = pp[cur];               // one b128 broadcast read
    float d[8];
#pragma unroll
    for (int t = 0; t < 4; ++t) {
      fl2 dx = mx[t] - w.x;           // v_pk ops; per-comp RN == scalar (np)
      fl2 dy = my[t] - w.y;
      fl2 dz = mz[t] - w.z;
      fl2 dd = (dx * dx + dy * dy) + dz * dz;   // np order, contract off
      fl2 dc = dist[t];
      float d0 = fminf(dc.x, dd.x);   // np.minimum
      float d1 = fminf(dc.y, dd.y);
      dist[t] = fl2{d0, d1};
      d[2 * t]     = d0;
      d[2 * t + 1] = d1;
    }
    // lane argmax: max tree + descending first-index scan (q asc = j asc)
    float m01 = fmaxf(d[0], d[1]), m23 = fmaxf(d[2], d[3]);
    float m45 = fmaxf(d[4], d[5]), m67 = fmaxf(d[6], d[7]);
    float bestv = fmaxf(fmaxf(m01, m23), fmaxf(m45, m67));
    int qsel = 7;
#pragma unroll
    for (int q = 6; q >= 0; --q)
      if (d[q] == bestv) qsel = q;    // descending -> lowest q (first max) wins
    int besti = tid + (qsel << 9);

    // wave max (f32 DPP chain; dist >= 0 so bits-order == value-order)
    float m = bestv;
    m = dpp_maxf<0x111>(m);   // row_shr:1
    m = dpp_maxf<0x112>(m);   // row_shr:2
    m = dpp_maxf<0x114>(m);   // row_shr:4
    m = dpp_maxf<0x118>(m);   // row_shr:8
    m = dpp_maxf<0x142>(m);   // row_bcast:15
    m = dpp_maxf<0x143>(m);   // row_bcast:31  -> lane 63 has wave max
    float wm = __int_as_float(__builtin_amdgcn_readlane(__float_as_int(m), 63));
    // tie-break: min index among lanes attaining the wave max
    UI cand = (bestv == wm) ? (UI)besti : 0xFFFFFFFFu;
    cand = dpp_minu<0x111>(cand);
    cand = dpp_minu<0x112>(cand);
    cand = dpp_minu<0x114>(cand);
    cand = dpp_minu<0x118>(cand);
    cand = dpp_minu<0x142>(cand);
    cand = dpp_minu<0x143>(cand);
    UI widx = (UI)__builtin_amdgcn_readlane((int)cand, 63);

    // cross-wave: one u64 key per wave (larger d wins; tie -> smaller idx)
    ULL key = ((ULL)__float_as_uint(wm) << 32) | (ULL)(~widx);
    const int buf = k & 1;            // double buffer: no read/write race
    if (lane == 0) slots[buf][wv] = key;
    __syncthreads();
    const ULL* sp = slots[buf];
    ULL mk = sp[0];
#pragma unroll
    for (int i = 1; i < 8; ++i) { ULL s = sp[i]; if (s > mk) mk = s; }
    int winner = (int)(~(UI)mk);
    if (tid == 0) selstash[b * MB_SEL + k] = (float)winner;
    cur = winner;
  }
}

// ---------------------------------------------------------------------------
// Kernel 2: fused radius (f64) + MFMA-f16 MLP + masked max (unchanged r10).
// ---------------------------------------------------------------------------
__global__ __launch_bounds__(256, 3) void conv_kernel(
    const float* __restrict__ x, const float* __restrict__ pos,
    const float* __restrict__ b1, const float* __restrict__ b2,
    const float* __restrict__ b3, const f16* __restrict__ ws,
    const float* __restrict__ selstash, float* __restrict__ out_x,
    float* __restrict__ out_pos, float* __restrict__ out_batch) {
  __shared__ f16 featA[64 * 104];   // [row][k<96], stride 104
  __shared__ f16 h1s[64 * 136];     // [row][k<128], stride 136
  __shared__ f16 h2s[64 * 136];
  __shared__ float pmax[256];
  __shared__ ULL masks[64];
  __shared__ int nbrS[KNBR];
  __shared__ int nvS;

  const int tid  = threadIdx.x;
  const int lane = tid & 63;
  const int wv   = tid >> 6;
  const int c    = blockIdx.x;
  const int b    = c >> 10;
  const int s    = ((int)selstash[c]) & (NB_PTS - 1);
  const size_t qb = ((size_t)(b * NB_PTS + s)) * 3;
  const float qxf = pos[qb], qyf = pos[qb + 1], qzf = pos[qb + 2];
  const double qx = (double)qxf, qy = (double)qyf, qz = (double)qzf;
  const double RR = 0.2 * 0.2;

  // ---- radius: in-ball bitmask over all 4096 points ----
  for (int it = 0; it < 16; ++it) {
    const int ch = wv * 16 + it;
    const int j  = ch * 64 + lane;
    const size_t pb = ((size_t)b * NB_PTS + j) * 3;
    double d2 = d2_np64((double)pos[pb] - qx, (double)pos[pb + 1] - qy,
                        (double)pos[pb + 2] - qz);
    ULL m = __ballot(d2 <= RR);
    if (lane == 0) masks[ch] = m;
  }
  __syncthreads();

  // ---- B1/B2 register preload (overlaps wave-0 extraction) ----
  const int n    = lane & 15;
  const int quad = lane >> 4;
  h8 B1[2][3], B2[2][4];
  float bv1[2], bv2[2], bv3[4];
#pragma unroll
  for (int ct = 0; ct < 2; ++ct) {
    const int col = (2 * wv + ct) * 16 + n;
    bv1[ct] = b1[col];
    bv2[ct] = b2[col];
#pragma unroll
    for (int kt = 0; kt < 3; ++kt)
      B1[ct][kt] = *(const h8*)(ws + col * 96 + kt * 32 + quad * 8);
#pragma unroll
    for (int kt = 0; kt < 4; ++kt)
      B2[ct][kt] = *(const h8*)(ws + WT2_OFF + col * 128 + kt * 32 + quad * 8);
  }
#pragma unroll
  for (int ct = 0; ct < 4; ++ct) bv3[ct] = b3[(4 * wv + ct) * 16 + n];

  // ---- wave 0: first-64 in-ball extraction (ascending index) ----
  if (tid < 64) {
    ULL m = masks[tid];
    int pc = __popcll(m);
    int incl = pc;
#pragma unroll
    for (int off = 1; off < 64; off <<= 1) {
      int o = __shfl_up(incl, off, 64);
      if (tid >= off) incl += o;
    }
    int base = incl - pc;
    int tot  = __shfl(incl, 63, 64);
    int nvw  = min(tot, KNBR);
    if (tid == 63) nvS = nvw;
    int slot = base;
    ULL mm = m;
    while (mm && slot < KNBR) {
      int bit = __ffsll(mm) - 1;
      nbrS[slot++] = tid * 64 + bit;
      mm &= mm - 1;
    }
    if (tid >= nvw) nbrS[tid] = s;
  }
  __syncthreads();
  const int nv = nvS;

  // ---- gather: feat=[x_j, pos_j-pos_i, 0-pad] as f16, rows 0..63 ----
  {
    const int r = tid >> 2;           // row
    const int part = tid & 3;         // 16 x-feats each
    const int g = nbrS[r];
    const float* xrow = x + (((size_t)(b * NB_PTS + g)) << 6) + part * 16;
    float4 u0 = *(const float4*)(xrow);
    float4 u1 = *(const float4*)(xrow + 4);
    float4 u2 = *(const float4*)(xrow + 8);
    float4 u3 = *(const float4*)(xrow + 12);
    h8 o0, o1;
    o0[0]=(f16)u0.x; o0[1]=(f16)u0.y; o0[2]=(f16)u0.z; o0[3]=(f16)u0.w;
    o0[4]=(f16)u1.x; o0[5]=(f16)u1.y; o0[6]=(f16)u1.z; o0[7]=(f16)u1.w;
    o1[0]=(f16)u2.x; o1[1]=(f16)u2.y; o1[2]=(f16)u2.z; o1[3]=(f16)u2.w;
    o1[4]=(f16)u3.x; o1[5]=(f16)u3.y; o1[6]=(f16)u3.z; o1[7]=(f16)u3.w;
    *(h8*)(featA + r * 104 + part * 16)     = o0;
    *(h8*)(featA + r * 104 + part * 16 + 8) = o1;
    if (part == 3) {
      size_t gb = ((size_t)(b * NB_PTS + g)) * 3;
      h8 rv = {(f16)0.f,(f16)0.f,(f16)0.f,(f16)0.f,(f16)0.f,(f16)0.f,(f16)0.f,(f16)0.f};
      rv[0] = (f16)(pos[gb]     - qxf);
      rv[1] = (f16)(pos[gb + 1] - qyf);
      rv[2] = (f16)(pos[gb + 2] - qzf);
      h8 z = {(f16)0.f,(f16)0.f,(f16)0.f,(f16)0.f,(f16)0.f,(f16)0.f,(f16)0.f,(f16)0.f};
      *(h8*)(featA + r * 104 + 64) = rv;
      *(h8*)(featA + r * 104 + 72) = z;
      *(h8*)(featA + r * 104 + 80) = z;
      *(h8*)(featA + r * 104 + 88) = z;
    }
  }
  __syncthreads();

  // ---- L1: 67(->96) -> 128 ; wave w owns cols [32w,32w+32) ----
#pragma unroll
  for (int at = 0; at < 4; ++at) {
#pragma unroll
    for (int ct = 0; ct < 2; ++ct) {
      f32x4 acc = {0.f, 0.f, 0.f, 0.f};
#pragma unroll
      for (int kt = 0; kt < 3; ++kt) {
        h8 a = *(const h8*)(featA + (at * 16 + n) * 104 + kt * 32 + quad * 8);
        acc = __builtin_amdgcn_mfma_f32_16x16x32_f16(a, B1[ct][kt], acc, 0, 0, 0);
      }
      const int col = (2 * wv + ct) * 16 + n;
#pragma unroll
      for (int r = 0; r < 4; ++r)
        h1s[(at * 16 + quad * 4 + r) * 136 + col] = (f16)fmaxf(acc[r] + bv1[ct], 0.f);
    }
  }
  __syncthreads();

  // ---- L2: 128 -> 128 ----
#pragma unroll
  for (int at = 0; at < 4; ++at) {
#pragma unroll
    for (int ct = 0; ct < 2; ++ct) {
      f32x4 acc = {0.f, 0.f, 0.f, 0.f};
#pragma unroll
      for (int kt = 0; kt < 4; ++kt) {
        h8 a = *(const h8*)(h1s + (at * 16 + n) * 136 + kt * 32 + quad * 8);
        acc = __builtin_amdgcn_mfma_f32_16x16x32_f16(a, B2[ct][kt], acc, 0, 0, 0);
      }
      const int col = (2 * wv + ct) * 16 + n;
#pragma unroll
      for (int r = 0; r < 4; ++r)
        h2s[(at * 16 + quad * 4 + r) * 136 + col] = (f16)fmaxf(acc[r] + bv2[ct], 0.f);
    }
  }
  __syncthreads();

  // ---- L3: 128 -> 256, B3 streamed from L2; fused bias+relu+valid+max ----
  float vm[4] = {0.f, 0.f, 0.f, 0.f};   // valid max >= 0 (relu, nv>=1)
#pragma unroll
  for (int at = 0; at < 4; ++at) {
#pragma unroll
    for (int ct = 0; ct < 4; ++ct) {
      const int col = (4 * wv + ct) * 16 + n;
      f32x4 acc = {0.f, 0.f, 0.f, 0.f};
#pragma unroll
      for (int kt = 0; kt < 4; ++kt) {
        h8 a = *(const h8*)(h2s + (at * 16 + n) * 136 + kt * 32 + quad * 8);
        h8 wfr = *(const h8*)(ws + WT3_OFF + col * 128 + kt * 32 + quad * 8);
        acc = __builtin_amdgcn_mfma_f32_16x16x32_f16(a, wfr, acc, 0, 0, 0);
      }
#pragma unroll
      for (int r = 0; r < 4; ++r) {
        float h = fmaxf(acc[r] + bv3[ct], 0.f);
        const int row = at * 16 + quad * 4 + r;
        vm[ct] = fmaxf(vm[ct], row < nv ? h : 0.f);
      }
    }
  }
#pragma unroll
  for (int ct = 0; ct < 4; ++ct) {
    vm[ct] = fmaxf(vm[ct], __shfl_xor(vm[ct], 16, 64));
    vm[ct] = fmaxf(vm[ct], __shfl_xor(vm[ct], 32, 64));
  }
  if (quad == 0) {
#pragma unroll
    for (int ct = 0; ct < 4; ++ct) pmax[wv * 64 + ct * 16 + n] = vm[ct];
  }
  __syncthreads();

  out_x[(size_t)c * 256 + tid] = pmax[tid];
  if (tid < 3) out_pos[c * 3 + tid] = pos[qb + tid];
  if (tid == 0) out_batch[c] = (float)b;   // overwrite sel stash
}

extern "C" void kernel_launch(void* const* d_in, const int* in_sizes, int n_in,
                              void* d_out, int out_size, void* d_ws, size_t ws_size,
                              hipStream_t stream) {
  const float* x   = (const float*)d_in[0];
  const float* pos = (const float*)d_in[1];
  // d_in[2] = batch (int32), unused (layout known)
  const float* W1 = (const float*)d_in[3];
  const float* b1 = (const float*)d_in[4];
  const float* W2 = (const float*)d_in[5];
  const float* b2 = (const float*)d_in[6];
  const float* W3 = (const float*)d_in[7];
  const float* b3 = (const float*)d_in[8];

  float* out = (float*)d_out;
  float* out_pos   = out + (size_t)NCENT * 256;
  float* out_batch = out_pos + (size_t)NCENT * 3;
  f16* ws = (f16*)d_ws;   // 122880 B of f16 weights

  fps_prep_kernel<<<NCLOUD + PREP_BLOCKS, 512, 0, stream>>>(pos, out_batch,
                                                            W1, W2, W3, ws);
  conv_kernel<<<NCENT, 256, 0, stream>>>(x, pos, b1, b2, b3, ws,
                                         out_batch, out, out_pos, out_batch);
}